// Round 4
// baseline (522.331 us; speedup 1.0000x reference)
//
#include <hip/hip_runtime.h>
#include <hip/hip_cooperative_groups.h>

namespace cg = cooperative_groups;

namespace {

constexpr int B = 128, N = 2048, E = 32768;
constexpr int LOG2N = 11, LOG2E = 15;
constexpr int QE = E / 4;          // edges per quarter block = 8192
constexpr int LOG2QE = 13;

// ws layout (bytes)
constexpr size_t OFF_H0 = 0;                     // B*N float4 = 4 MB
constexpr size_t OFF_H1 = 4u * 1024 * 1024;      // B*N float4 = 4 MB
constexpr size_t OFF_S8 = 8u * 1024 * 1024;      // B*4 quarters * QE int2 = 32 MB
constexpr size_t OFF_RP = 40u * 1024 * 1024;     // B*4*(N+1) int ~ 4.2 MB

struct Params {
  const float4* x;
  const int*    edge_index;
  const float*  edge_time;
  const float*  timestamp;
  const int*    src_index;
  const int*    dst_index;
  const float*  tw;
  const float*  tb;
  const float*  Wq;
  const float*  Wk;
  const float*  Wv;
  const float*  Wo;
  const float*  bo;
  const float*  W_lin;
  const float*  b_lin;
  float4* h0;
  float4* h1;
  int2*   sorted8;
  int*    row_ptr;
  float*  out;
};

__device__ __forceinline__ float hw_cos(float s)  { float d; asm("v_cos_f32 %0, %1" : "=v"(d) : "v"(s)); return d; }
__device__ __forceinline__ float hw_exp2(float s) { float d; asm("v_exp_f32 %0, %1" : "=v"(d) : "v"(s)); return d; }

// LDS overlay: sort phase needs 73.8 KB, layer phase 32 KB. One block/CU.
struct SortS { int cnt[N]; int wsum[16]; int2 rec[QE]; };

// R3's layer body, parameterized; cursor geometry (s*/c*) passed in regs
// (computed once after the sort phase, reused by both layers).
__device__ __forceinline__ void layer_phase(
    const Params& P, int b, int n, int t, int l,
    const float4* __restrict__ h_in, float4* __restrict__ h_out, float4* lh,
    int s0, int s1, int s2, int s3, int c0, int c1, int c2, int c3) {
  const float4* hb = h_in + (((size_t)b) << LOG2N);
  lh[t] = hb[t];
  lh[t + 1024] = hb[t + 1024];

  const float* tw = P.tw;
  const float* tb = P.tb;
  const float* Wq = P.Wq + l * 16;
  const float* Wk = P.Wk + l * 32;
  const float* Wv = P.Wv + l * 32;
  const float* Wo = P.Wo + l * 16;
  const float* bo = P.bo + l * 4;

  constexpr float INV2PI = 0.15915494309189535f;
  constexpr float QSCALE = 0.70710678118654752f * 1.4426950408889634f;  // rs2*log2e
  float twf2[4], tbf2[4], wq[16], wkh[16], wkp[16], wvh[16], wvp[16];
#pragma unroll
  for (int j = 0; j < 4; j++) { twf2[j] = tw[j] * INV2PI; tbf2[j] = tb[j] * INV2PI; }
#pragma unroll
  for (int j = 0; j < 16; j++) wq[j] = Wq[j];
#pragma unroll
  for (int j = 0; j < 16; j++) { wkh[j] = Wk[j]; wkp[j] = Wk[16 + j]; }
#pragma unroll
  for (int j = 0; j < 16; j++) { wvh[j] = Wv[j]; wvp[j] = Wv[16 + j]; }
  __syncthreads();

  {
    float4 hn = lh[n];
    float q0 = (hn.x * wq[0] + hn.y * wq[4] + hn.z * wq[8]  + hn.w * wq[12]) * QSCALE;
    float q1 = (hn.x * wq[1] + hn.y * wq[5] + hn.z * wq[9]  + hn.w * wq[13]) * QSCALE;
    float q2 = (hn.x * wq[2] + hn.y * wq[6] + hn.z * wq[10] + hn.w * wq[14]) * QSCALE;
    float q3 = (hn.x * wq[3] + hn.y * wq[7] + hn.z * wq[11] + hn.w * wq[15]) * QSCALE;
#pragma unroll
    for (int i = 0; i < 4; i++) {
      wq[i]      = q0 * wkh[i * 4 + 0] + q1 * wkh[i * 4 + 1];  // wH0
      wq[4 + i]  = q2 * wkh[i * 4 + 2] + q3 * wkh[i * 4 + 3];  // wH1
      wq[8 + i]  = q0 * wkp[i * 4 + 0] + q1 * wkp[i * 4 + 1];  // wA
      wq[12 + i] = q2 * wkp[i * 4 + 2] + q3 * wkp[i * 4 + 3];  // wB
    }
  }

  int stage = 0;
  int total = c0 + c1 + c2 + c3;
  int addr = ((b * 4 + 0) << LOG2QE) + s0, rem = c0;
  int b1 = ((b * 4 + 1) << LOG2QE) + s1;
  int b2 = ((b * 4 + 2) << LOG2QE) + s2;
  int b3 = ((b * 4 + 3) << LOG2QE) + s3;
  while (rem <= 0 && stage < 3) {
    ++stage;
    addr = (stage == 1) ? b1 : (stage == 2) ? b2 : b3;
    rem  = (stage == 1) ? c1 : (stage == 2) ? c2 : c3;
  }

#define ADV() do { ++addr; --rem;                                   \
    while (rem <= 0 && stage < 3) { ++stage;                        \
      addr = (stage == 1) ? b1 : (stage == 2) ? b2 : b3;            \
      rem  = (stage == 1) ? c1 : (stage == 2) ? c2 : c3; } } while (0)

  float s0v = 0.f, s1v = 0.f, a00 = 0.f, a01 = 0.f, a10 = 0.f, a11 = 0.f;

  // depth-4 record pipeline; junk prefetch past segment ends stays inside the
  // sorted8/row_ptr ws region (valid memory) and never reaches accumulators.
  const int2* __restrict__ srt = P.sorted8;
  int2 r0 = srt[addr]; ADV();
  int2 r1 = srt[addr]; ADV();
  int2 r2 = srt[addr]; ADV();
  int2 r3 = srt[addr]; ADV();
  float4 hsN = lh[r0.x & (N - 1)];

  for (int it = 0; it < total; ++it) {
    int2 cur = r0;
    float4 hs = hsN;
    r0 = r1; r1 = r2; r2 = r3;
    r3 = srt[addr]; ADV();
    hsN = lh[r0.x & (N - 1)];

    float dt = __int_as_float(cur.y);
    float ph0 = hw_cos(dt * twf2[0] + tbf2[0]);
    float ph1 = hw_cos(dt * twf2[1] + tbf2[1]);
    float ph2 = hw_cos(dt * twf2[2] + tbf2[2]);
    float ph3 = hw_cos(dt * twf2[3] + tbf2[3]);

    float l0 = hs.x * wq[0] + hs.y * wq[1] + hs.z * wq[2]  + hs.w * wq[3]
             + ph0 * wq[8] + ph1 * wq[9] + ph2 * wq[10] + ph3 * wq[11];
    float l1 = hs.x * wq[4] + hs.y * wq[5] + hs.z * wq[6]  + hs.w * wq[7]
             + ph0 * wq[12] + ph1 * wq[13] + ph2 * wq[14] + ph3 * wq[15];

    float p0 = hw_exp2(l0);
    float p1 = hw_exp2(l1);

    float v0 = hs.x * wvh[0] + hs.y * wvh[4] + hs.z * wvh[8]  + hs.w * wvh[12]
             + ph0 * wvp[0] + ph1 * wvp[4] + ph2 * wvp[8]  + ph3 * wvp[12];
    float v1 = hs.x * wvh[1] + hs.y * wvh[5] + hs.z * wvh[9]  + hs.w * wvh[13]
             + ph0 * wvp[1] + ph1 * wvp[5] + ph2 * wvp[9]  + ph3 * wvp[13];
    float v2 = hs.x * wvh[2] + hs.y * wvh[6] + hs.z * wvh[10] + hs.w * wvh[14]
             + ph0 * wvp[2] + ph1 * wvp[6] + ph2 * wvp[10] + ph3 * wvp[14];
    float v3 = hs.x * wvh[3] + hs.y * wvh[7] + hs.z * wvh[11] + hs.w * wvh[15]
             + ph0 * wvp[3] + ph1 * wvp[7] + ph2 * wvp[11] + ph3 * wvp[15];

    s0v += p0; a00 += p0 * v0; a01 += p0 * v1;
    s1v += p1; a10 += p1 * v2; a11 += p1 * v3;
  }
#undef ADV

  float den0 = (s0v == 0.f) ? 1.f : s0v;
  float den1 = (s1v == 0.f) ? 1.f : s1v;
  float at0 = a00 / den0, at1 = a01 / den0, at2 = a10 / den1, at3 = a11 / den1;

  float wof[16], bof[4];
#pragma unroll
  for (int j = 0; j < 16; j++) wof[j] = Wo[j];
#pragma unroll
  for (int j = 0; j < 4; j++) bof[j] = bo[j];

  float4 hn = lh[n];
  float o0 = bof[0] + at0 * wof[0] + at1 * wof[4] + at2 * wof[8]  + at3 * wof[12];
  float o1 = bof[1] + at0 * wof[1] + at1 * wof[5] + at2 * wof[9]  + at3 * wof[13];
  float o2 = bof[2] + at0 * wof[2] + at1 * wof[6] + at2 * wof[10] + at3 * wof[14];
  float o3 = bof[3] + at0 * wof[3] + at1 * wof[7] + at2 * wof[11] + at3 * wof[15];
  h_out[(((size_t)b) << LOG2N) + n] =
      make_float4(fmaxf(hn.x + o0, 0.f), fmaxf(hn.y + o1, 0.f),
                  fmaxf(hn.z + o2, 0.f), fmaxf(hn.w + o3, 0.f));
}

// One cooperative kernel: sort -> layer1 -> layer2 -> final.
// 256 blocks x 1024 threads, 1 block/CU (co-resident, cooperative launch).
// Sibling pairing: blocks p and p+8 (same XCD under %8 round-robin) handle
// the same batch -> the CSR read in the layer phases is same-XCD L2-warm.
__global__ __launch_bounds__(1024) void fused_kernel(Params P) {
  __shared__ __align__(16) char smem[sizeof(SortS)];
  int p = blockIdx.x, t = threadIdx.x;
  int xcd = p & 7, slot = p >> 3;          // 32 slots per XCD
  int b = xcd * 16 + (slot >> 1);          // 16 batches per XCD
  int half = slot & 1;

  // ---------------- phase S: sort quarters {2*half, 2*half+1} ----------------
  {
    SortS& S = *reinterpret_cast<SortS*>(smem);
    float ts = P.timestamp[b];
    for (int qi = 0; qi < 2; ++qi) {
      int q = 2 * half + qi;
      int blk = b * 4 + q;
      S.cnt[t] = 0; S.cnt[t + 1024] = 0;
      __syncthreads();

      const int* src_arr = P.edge_index + (((size_t)(2 * b)) << LOG2E) + q * QE;
      const int* dst_arr = P.edge_index + (((size_t)(2 * b + 1)) << LOG2E) + q * QE;
      const float* et    = P.edge_time + (((size_t)b) << LOG2E) + q * QE;

      // single-pass edge staging into registers (static indices)
      int srcv[8], dstv[8]; float dtv[8];
#pragma unroll
      for (int k = 0; k < 8; ++k) {
        int e = t + k * 1024;
        srcv[k] = src_arr[e];
        dstv[k] = dst_arr[e];
        dtv[k]  = ts - et[e];
      }
#pragma unroll
      for (int k = 0; k < 8; ++k) atomicAdd(&S.cnt[dstv[k]], 1);
      __syncthreads();

      // exclusive scan of 2048 counts: wave shuffle + 16-partial scan
      int i0 = 2 * t, i1 = 2 * t + 1;
      int l0 = S.cnt[i0], l1 = S.cnt[i1];
      int sum = l0 + l1;
      int lane = t & 63, wid = t >> 6;
      int incl = sum;
#pragma unroll
      for (int d = 1; d < 64; d <<= 1) {
        int v = __shfl_up(incl, d, 64);
        if (lane >= d) incl += v;
      }
      if (lane == 63) S.wsum[wid] = incl;
      __syncthreads();
      if (t < 16) {
        int v = S.wsum[t];
        int inc = v;
#pragma unroll
        for (int d = 1; d < 16; d <<= 1) {
          int u = __shfl_up(inc, d, 16);
          if (t >= d) inc += u;
        }
        S.wsum[t] = inc - v;
      }
      __syncthreads();
      int run = S.wsum[wid] + (incl - sum);
      int run2 = run + l0;
      int* rp = P.row_ptr + (size_t)blk * (N + 1);
      rp[i0] = run;
      rp[i1] = run2;
      if (t == 1023) rp[N] = QE;
      S.cnt[i0] = run;
      S.cnt[i1] = run2;
      __syncthreads();

      // scatter into LDS CSR from registers
#pragma unroll
      for (int k = 0; k < 8; ++k) {
        int pos = atomicAdd(&S.cnt[dstv[k]], 1);
        S.rec[pos] = make_int2(srcv[k], __float_as_int(dtv[k]));
      }
      __syncthreads();

      // coalesced stream-out
      const int4* rec4 = (const int4*)S.rec;
      int4* out4 = (int4*)(P.sorted8 + (((size_t)blk) << LOG2QE));
      for (int i = t; i < QE / 2; i += 1024) out4[i] = rec4[i];
      __syncthreads();
    }
  }
  __threadfence();
  cg::this_grid().sync();

  // cursor geometry, computed once, reused by both layers
  int n = half * 1024 + t;
  int s0, s1, s2, s3, c0, c1, c2, c3;
  {
    const int* rp0 = P.row_ptr + (size_t)(b * 4 + 0) * (N + 1);
    const int* rp1 = P.row_ptr + (size_t)(b * 4 + 1) * (N + 1);
    const int* rp2 = P.row_ptr + (size_t)(b * 4 + 2) * (N + 1);
    const int* rp3 = P.row_ptr + (size_t)(b * 4 + 3) * (N + 1);
    s0 = rp0[n]; c0 = rp0[n + 1] - s0;
    s1 = rp1[n]; c1 = rp1[n + 1] - s1;
    s2 = rp2[n]; c2 = rp2[n + 1] - s2;
    s3 = rp3[n]; c3 = rp3[n + 1] - s3;
  }

  float4* lh = reinterpret_cast<float4*>(smem);

  // ---------------- phase L1 ----------------
  layer_phase(P, b, n, t, 0, P.x, P.h1, lh, s0, s1, s2, s3, c0, c1, c2, c3);
  __threadfence();
  cg::this_grid().sync();

  // ---------------- phase L2 ----------------
  layer_phase(P, b, n, t, 1, P.h1, P.h0, lh, s0, s1, s2, s3, c0, c1, c2, c3);
  __threadfence();
  cg::this_grid().sync();

  // ---------------- phase F ----------------
  if (p == 0 && t < B) {
    int bb = t;
    float4 sx = P.h0[(((size_t)bb) << LOG2N) + P.src_index[bb]];
    float4 dx = P.h0[(((size_t)bb) << LOG2N) + P.dst_index[bb]];
    float ts = P.timestamp[bb];
    float f[12];
    f[0] = sx.x; f[1] = sx.y; f[2] = sx.z; f[3] = sx.w;
    f[4] = dx.x; f[5] = dx.y; f[6] = dx.z; f[7] = dx.w;
#pragma unroll
    for (int j = 0; j < 4; j++) f[8 + j] = __cosf(ts * P.tw[j] + P.tb[j]);
#pragma unroll
    for (int c = 0; c < 2; c++) {
      float o = P.b_lin[c];
#pragma unroll
      for (int j = 0; j < 12; j++) o += f[j] * P.W_lin[j * 2 + c];
      P.out[bb * 2 + c] = o;
    }
  }
}

}  // namespace

extern "C" void kernel_launch(void* const* d_in, const int* in_sizes, int n_in,
                              void* d_out, int out_size, void* d_ws, size_t ws_size,
                              hipStream_t stream) {
  (void)in_sizes; (void)n_in; (void)out_size; (void)ws_size;
  char* ws = (char*)d_ws;

  Params hp;
  hp.x          = (const float4*)d_in[0];
  hp.edge_index = (const int*)d_in[1];
  hp.edge_time  = (const float*)d_in[2];
  hp.timestamp  = (const float*)d_in[3];
  hp.src_index  = (const int*)d_in[4];
  hp.dst_index  = (const int*)d_in[5];
  hp.tw         = (const float*)d_in[6];
  hp.tb         = (const float*)d_in[7];
  hp.Wq         = (const float*)d_in[8];
  hp.Wk         = (const float*)d_in[9];
  hp.Wv         = (const float*)d_in[10];
  hp.Wo         = (const float*)d_in[11];
  hp.bo         = (const float*)d_in[12];
  hp.W_lin      = (const float*)d_in[13];
  hp.b_lin      = (const float*)d_in[14];
  hp.h0         = (float4*)(ws + OFF_H0);
  hp.h1         = (float4*)(ws + OFF_H1);
  hp.sorted8    = (int2*)(ws + OFF_S8);
  hp.row_ptr    = (int*)(ws + OFF_RP);
  hp.out        = (float*)d_out;

  void* kargs[] = { (void*)&hp };
  hipLaunchCooperativeKernel((void*)fused_kernel, dim3(2 * B), dim3(1024),
                             kargs, 0, stream);
}